// Round 3
// baseline (777.186 us; speedup 1.0000x reference)
//
#include <hip/hip_runtime.h>
#include <cstdint>
#include <cstddef>
#include <cmath>

#define N_TOK 2048
#define HDIM  2048
#define NEXP  16
#define IDIM  1024
#define SIDIM 2048
#define NTHREADS 256

typedef __attribute__((ext_vector_type(8))) short bf16x8;
typedef __attribute__((ext_vector_type(4))) float f32x4;

__device__ __forceinline__ uint32_t f2bf_u(float f) {
    union { float f; uint32_t u; } v; v.f = f;
    return (v.u + 0x7FFFu + ((v.u >> 16) & 1u)) >> 16;   // RNE
}

// 2x f32 -> packed bf16 (RNE), single instruction on gfx950.
__device__ __forceinline__ uint32_t cvtpk(float lo, float hi) {
    uint32_t r;
    asm("v_cvt_pk_bf16_f32 %0, %1, %2" : "=v"(r) : "v"(lo), "v"(hi));
    return r;
}

// async global->LDS, 16B per lane. LDS dest = uniform base + lane*16.
__device__ __forceinline__ void gload_lds16(const void* g, void* l) {
    __builtin_amdgcn_global_load_lds(
        (const __attribute__((address_space(1))) uint32_t*)g,
        (__attribute__((address_space(3))) uint32_t*)l, 16, 0, 0);
}

// Legacy 64B-row swizzle for the fallback kernels (4 chunks/row).
__device__ __forceinline__ int swz(int row, int c) {
    return row * 4 + (c ^ ((row >> 1) & 3));
}

// ------------------------------------------------------------ x -> bf16 ----
__global__ __launch_bounds__(NTHREADS)
void convert_x_kernel(const float* __restrict__ x, unsigned short* __restrict__ xb)
{
    const size_t i = ((size_t)blockIdx.x * NTHREADS + threadIdx.x) * 8;
    float4 a = *(const float4*)(x + i);
    float4 b = *(const float4*)(x + i + 4);
    uint4 w = make_uint4(cvtpk(a.x, a.y), cvtpk(a.z, a.w),
                         cvtpk(b.x, b.y), cvtpk(b.z, b.w));
    *(uint4*)(xb + i) = w;
}

// ------------------------------------------- W fp32 [K][N] -> bf16 [N][K] --
// 64x64 tile via LDS. BW-bound; runs once per call over all weights.
#define TP 68   // padded LDS row stride in shorts (136B: 8B-aligned, bank-spread)
__global__ __launch_bounds__(NTHREADS)
void transpose_w(const float* __restrict__ src, unsigned short* __restrict__ dst,
                 const int K, const int N)
{
    const size_t moff = (size_t)blockIdx.z * K * N;
    src += moff; dst += moff;
    const int k0 = blockIdx.y * 64;
    const int n0 = blockIdx.x * 64;
    __shared__ short t[64 * TP];
    const int tid = threadIdx.x;

    // read 64(k) x 64(n) fp32, convert to bf16 into LDS [k][n]
    {
        const int c  = tid & 15;         // float4 column group
        const int r0 = (tid >> 4) * 4;   // 4 rows per thread
#pragma unroll
        for (int it = 0; it < 4; ++it) {
            const int r = r0 + it;
            float4 v = *(const float4*)(src + (size_t)(k0 + r) * N + n0 + c * 4);
            uint2 p; p.x = cvtpk(v.x, v.y); p.y = cvtpk(v.z, v.w);
            *(uint2*)(&t[r * TP + c * 4]) = p;
        }
    }
    __syncthreads();

    // write 64(n) x 64(k) bf16, 16B per chunk
    {
        const int c2  = tid & 7;         // 8-wide k chunk
        const int nr0 = tid >> 3;        // 0..31
#pragma unroll
        for (int it = 0; it < 2; ++it) {
            const int n = nr0 + it * 32;
            union { unsigned short v[8]; uint4 u4; } tmp;
#pragma unroll
            for (int j = 0; j < 8; ++j) tmp.v[j] = (unsigned short)t[(c2 * 8 + j) * TP + n];
            *(uint4*)(dst + (size_t)(n0 + n) * K + k0 + c2 * 8) = tmp.u4;
        }
    }
}

// ---------------------------------------------------------------- router ----
__global__ __launch_bounds__(NTHREADS)
void router_kernel(const float* __restrict__ x,
                   const float* __restrict__ rw,
                   float* __restrict__ logits_out,
                   int* __restrict__ cnt,
                   int* __restrict__ tok_list,
                   float* __restrict__ wt_list)
{
    const int n = blockIdx.x;
    const int tid = threadIdx.x;
    const float* xr = x + (size_t)n * HDIM;

    float acc[NEXP];
#pragma unroll
    for (int e = 0; e < NEXP; ++e) acc[e] = 0.f;

    for (int h = tid; h < HDIM; h += NTHREADS) {
        float xv = xr[h];
#pragma unroll
        for (int e = 0; e < NEXP; ++e) acc[e] += xv * rw[(size_t)e * HDIM + h];
    }

    __shared__ float red[NEXP][NTHREADS];
#pragma unroll
    for (int e = 0; e < NEXP; ++e) red[e][tid] = acc[e];
    __syncthreads();
    for (int s = NTHREADS / 2; s > 0; s >>= 1) {
        if (tid < s) {
#pragma unroll
            for (int e = 0; e < NEXP; ++e) red[e][tid] += red[e][tid + s];
        }
        __syncthreads();
    }

    if (tid < NEXP) logits_out[(size_t)n * NEXP + tid] = red[tid][0];

    if (tid == 0) {
        float l[NEXP];
#pragma unroll
        for (int e = 0; e < NEXP; ++e) l[e] = red[e][0];
        int e0 = 0;
#pragma unroll
        for (int e = 1; e < NEXP; ++e) if (l[e] > l[e0]) e0 = e;
        int e1 = (e0 == 0) ? 1 : 0;
#pragma unroll
        for (int e = 0; e < NEXP; ++e)
            if (e != e0 && l[e] > l[e1]) e1 = e;
        float t = expf(l[e1] - l[e0]);
        float s = 1.f + t;
        float rw0 = 1.f / s;
        float rw1 = t / s;
        int p0 = atomicAdd(&cnt[e0], 1);
        tok_list[e0 * N_TOK + p0] = n;
        wt_list[e0 * N_TOK + p0] = rw0;
        int p1 = atomicAdd(&cnt[e1], 1);
        tok_list[e1 * N_TOK + p1] = n;
        wt_list[e1 * N_TOK + p1] = rw1;
    }
}

__global__ void prefix_kernel(const int* __restrict__ cnt, int* __restrict__ base)
{
    if (threadIdx.x == 0) {
        int s = 0;
        for (int e = 0; e < NEXP; ++e) { base[e] = s; s += cnt[e]; }
    }
}

// ===================== FAST PATH: global_load_lds 2-phase pipeline ==========
// LDS tiles have 128B rows (64 bf16 k per row), 8 x 16B chunks per row.
// Logical chunk cl lives at physical chunk cl ^ (row&7)  (involution).
// Staged with pre-swizzled per-lane GLOBAL source; read with the same XOR.

// Dual GEMM + SwiGLU.  Tile 128m x 64n x 64k, 4 waves 2x2 (wave 64m x 32n).
//   z == 0 : shared expert (Icols=SIDIM, Y=Yshared)
//   z >= 1 : sparse expert e=z-1 (Icols=IDIM, gathered rows, Y=Ysparse)
__global__ __launch_bounds__(NTHREADS)
void dual_swiglu_gl(const unsigned short* __restrict__ Xb,    // bf16 [N_TOK][HDIM]
                    const unsigned short* __restrict__ WgT,   // bf16 [E][IDIM][HDIM]
                    const unsigned short* __restrict__ WuT,
                    const unsigned short* __restrict__ WsgT,  // bf16 [SIDIM][HDIM]
                    const unsigned short* __restrict__ WsuT,
                    unsigned short* __restrict__ Ysparse,     // bf16 [2*N_TOK][IDIM]
                    unsigned short* __restrict__ Yshared,     // bf16 [N_TOK][SIDIM]
                    const int* __restrict__ cnt,
                    const int* __restrict__ base,
                    const int* __restrict__ tok_list)
{
    const int z = blockIdx.z;
    const bool shared_path = (z == 0);
    const int e = z - 1;
    const int Icols = shared_path ? SIDIM : IDIM;
    const int m0 = blockIdx.y * 128;
    const int n0 = blockIdx.x * 64;
    if (n0 >= Icols) return;
    const int M = shared_path ? N_TOK : cnt[e];
    if (m0 >= M) return;
    const unsigned short* Wg = shared_path ? WsgT : WgT + (size_t)e * IDIM * HDIM;
    const unsigned short* Wu = shared_path ? WsuT : WuT + (size_t)e * IDIM * HDIM;
    unsigned short* Y = shared_path ? Yshared : Ysparse;
    const int yb = shared_path ? 0 : base[e];

    __shared__ short As[2][128 * 64];   // 16KB per buffer
    __shared__ short Gs[2][64 * 64];    //  8KB
    __shared__ short Us[2][64 * 64];    //  8KB   (total 64KB)

    const int tid  = threadIdx.x;
    const int lane = tid & 63;
    const int w    = tid >> 6;
    const int wm   = w >> 1;
    const int wn   = w & 1;
    const int l15  = lane & 15;
    const int q    = lane >> 4;
    const int lr   = lane >> 3;            // row within 8-row segment
    const int cl   = (lane & 7) ^ lr;      // logical chunk for this lane's slot

    // per-lane global sources (row fixed per thread; advance by k0 elements)
    const unsigned short* aSrc[4];
#pragma unroll
    for (int i = 0; i < 4; ++i) {
        const int row  = (w * 4 + i) * 8 + lr;           // 0..127
        const int slot = m0 + row;
        const int xrow = shared_path ? slot
                       : tok_list[e * N_TOK + (slot < M ? slot : M - 1)];
        aSrc[i] = Xb + (size_t)xrow * HDIM + cl * 8;
    }
    const unsigned short *gSrc[2], *uSrc[2];
#pragma unroll
    for (int i = 0; i < 2; ++i) {
        const int n = (w * 2 + i) * 8 + lr;              // 0..63
        gSrc[i] = Wg + (size_t)(n0 + n) * HDIM + cl * 8;
        uSrc[i] = Wu + (size_t)(n0 + n) * HDIM + cl * 8;
    }

    f32x4 accg[4][2], accu[4][2];
#pragma unroll
    for (int i = 0; i < 4; ++i)
#pragma unroll
        for (int j = 0; j < 2; ++j) {
            accg[i][j] = (f32x4){0.f, 0.f, 0.f, 0.f};
            accu[i][j] = (f32x4){0.f, 0.f, 0.f, 0.f};
        }

    auto stage = [&](int b, int k0) {
#pragma unroll
        for (int i = 0; i < 4; ++i)
            gload_lds16(aSrc[i] + k0, &As[b][(w * 4 + i) * 512]);
#pragma unroll
        for (int i = 0; i < 2; ++i) {
            gload_lds16(gSrc[i] + k0, &Gs[b][(w * 2 + i) * 512]);
            gload_lds16(uSrc[i] + k0, &Us[b][(w * 2 + i) * 512]);
        }
    };
    auto compute = [&](int b) {
#pragma unroll
        for (int kk = 0; kk < 2; ++kk) {
            bf16x8 af[4], bg[2], bu[2];
#pragma unroll
            for (int i = 0; i < 4; ++i) {
                const int row = wm * 64 + i * 16 + l15;
                const int c = (q + kk * 4) ^ (row & 7);
                af[i] = *(const bf16x8*)(&As[b][row * 64 + c * 8]);
            }
#pragma unroll
            for (int j = 0; j < 2; ++j) {
                const int row = wn * 32 + j * 16 + l15;
                const int c = (q + kk * 4) ^ (row & 7);
                bg[j] = *(const bf16x8*)(&Gs[b][row * 64 + c * 8]);
                bu[j] = *(const bf16x8*)(&Us[b][row * 64 + c * 8]);
            }
#pragma unroll
            for (int i = 0; i < 4; ++i)
#pragma unroll
                for (int j = 0; j < 2; ++j) {
                    accg[i][j] = __builtin_amdgcn_mfma_f32_16x16x32_bf16(af[i], bg[j], accg[i][j], 0, 0, 0);
                    accu[i][j] = __builtin_amdgcn_mfma_f32_16x16x32_bf16(af[i], bu[j], accu[i][j], 0, 0, 0);
                }
        }
    };

    // 2-phase counted-vmcnt pipeline (T3 minimum recipe)
    stage(0, 0);
    asm volatile("s_waitcnt vmcnt(0)" ::: "memory");
    __builtin_amdgcn_s_barrier();
    int cur = 0;
    const int NT = HDIM / 64;
    for (int t = 0; t < NT; ++t) {
        if (t + 1 < NT) stage(cur ^ 1, (t + 1) * 64);
        compute(cur);
        asm volatile("s_waitcnt vmcnt(0)" ::: "memory");
        __builtin_amdgcn_s_barrier();
        cur ^= 1;
    }

    // epilogue: silu(g)*u -> bf16
#pragma unroll
    for (int i = 0; i < 4; ++i) {
#pragma unroll
        for (int r = 0; r < 4; ++r) {
            const int slot = m0 + wm * 64 + i * 16 + q * 4 + r;
            if (slot < M) {
                unsigned short* yrow = Y + (size_t)(yb + slot) * Icols;
#pragma unroll
                for (int j = 0; j < 2; ++j) {
                    const int col = n0 + wn * 32 + j * 16 + l15;
                    float g = accg[i][j][r];
                    float u = accu[i][j][r];
                    float y = (g / (1.f + expf(-g))) * u;
                    yrow[col] = (unsigned short)f2bf_u(y);
                }
            }
        }
    }
}

// Down GEMM.  Tile 64m x 128n x 64k, 4 waves 2x2 (wave 32m x 64n).
//   z == 0 : out[m] += Ash[m] @ WsdT^T (K=SIDIM)
//   z >= 1 : out[tok[m]] += wt[m] * (Ysp[yb+m] @ WdT[e]^T) (K=IDIM)
__global__ __launch_bounds__(NTHREADS)
void down_gl(const unsigned short* __restrict__ Ash,   // bf16 [N_TOK][SIDIM]
             const unsigned short* __restrict__ Asp,   // bf16 [2*N_TOK][IDIM]
             const unsigned short* __restrict__ WsdT,  // bf16 [HDIM][SIDIM]
             const unsigned short* __restrict__ WdT,   // bf16 [E][HDIM][IDIM]
             float* __restrict__ out,
             const int* __restrict__ cnt,
             const int* __restrict__ base,
             const int* __restrict__ tok_list,
             const float* __restrict__ wt_list)
{
    const int z = blockIdx.z;
    const bool shared_path = (z == 0);
    const int e = z - 1;
    const int K = shared_path ? SIDIM : IDIM;
    const int m0 = blockIdx.y * 64;
    const int n0 = blockIdx.x * 128;
    const int M = shared_path ? N_TOK : cnt[e];
    if (m0 >= M) return;
    const unsigned short* A  = shared_path ? Ash : Asp;
    const unsigned short* WT = shared_path ? WsdT : WdT + (size_t)e * HDIM * IDIM;
    const int yb = shared_path ? 0 : base[e];

    __shared__ short As_[2][64 * 64];    //  8KB per buffer
    __shared__ short Bs_[2][128 * 64];   // 16KB   (total 48KB)

    const int tid  = threadIdx.x;
    const int lane = tid & 63;
    const int w    = tid >> 6;
    const int wm   = w >> 1;
    const int wn   = w & 1;
    const int l15  = lane & 15;
    const int q    = lane >> 4;
    const int lr   = lane >> 3;
    const int cl   = (lane & 7) ^ lr;

    const unsigned short* aSrc[2];
#pragma unroll
    for (int i = 0; i < 2; ++i) {
        const int row  = (w * 2 + i) * 8 + lr;           // 0..63
        const int slot = m0 + row;
        const int arow = yb + (slot < M ? slot : M - 1);
        aSrc[i] = A + (size_t)arow * K + cl * 8;
    }
    const unsigned short* bSrc[4];
#pragma unroll
    for (int i = 0; i < 4; ++i) {
        const int n = (w * 4 + i) * 8 + lr;              // 0..127
        bSrc[i] = WT + (size_t)(n0 + n) * K + cl * 8;
    }

    f32x4 acc[2][4];
#pragma unroll
    for (int i = 0; i < 2; ++i)
#pragma unroll
        for (int j = 0; j < 4; ++j) acc[i][j] = (f32x4){0.f, 0.f, 0.f, 0.f};

    auto stage = [&](int b, int k0) {
#pragma unroll
        for (int i = 0; i < 2; ++i)
            gload_lds16(aSrc[i] + k0, &As_[b][(w * 2 + i) * 512]);
#pragma unroll
        for (int i = 0; i < 4; ++i)
            gload_lds16(bSrc[i] + k0, &Bs_[b][(w * 4 + i) * 512]);
    };
    auto compute = [&](int b) {
#pragma unroll
        for (int kk = 0; kk < 2; ++kk) {
            bf16x8 af[2], bf[4];
#pragma unroll
            for (int i = 0; i < 2; ++i) {
                const int row = wm * 32 + i * 16 + l15;
                const int c = (q + kk * 4) ^ (row & 7);
                af[i] = *(const bf16x8*)(&As_[b][row * 64 + c * 8]);
            }
#pragma unroll
            for (int j = 0; j < 4; ++j) {
                const int row = wn * 64 + j * 16 + l15;
                const int c = (q + kk * 4) ^ (row & 7);
                bf[j] = *(const bf16x8*)(&Bs_[b][row * 64 + c * 8]);
            }
#pragma unroll
            for (int i = 0; i < 2; ++i)
#pragma unroll
                for (int j = 0; j < 4; ++j)
                    acc[i][j] = __builtin_amdgcn_mfma_f32_16x16x32_bf16(af[i], bf[j], acc[i][j], 0, 0, 0);
        }
    };

    stage(0, 0);
    asm volatile("s_waitcnt vmcnt(0)" ::: "memory");
    __builtin_amdgcn_s_barrier();
    int cur = 0;
    const int NT = K / 64;
    for (int t = 0; t < NT; ++t) {
        if (t + 1 < NT) stage(cur ^ 1, (t + 1) * 64);
        compute(cur);
        asm volatile("s_waitcnt vmcnt(0)" ::: "memory");
        __builtin_amdgcn_s_barrier();
        cur ^= 1;
    }

#pragma unroll
    for (int i = 0; i < 2; ++i) {
#pragma unroll
        for (int r = 0; r < 4; ++r) {
            const int slot = m0 + wm * 32 + i * 16 + q * 4 + r;
            if (slot >= M) continue;
            const int tok  = shared_path ? slot : tok_list[e * N_TOK + slot];
            const float wt = shared_path ? 1.f  : wt_list[e * N_TOK + slot];
            float* orow = out + (size_t)tok * HDIM;
#pragma unroll
            for (int j = 0; j < 4; ++j) {
                const int col = n0 + wn * 64 + j * 16 + l15;
                atomicAdd(&orow[col], wt * acc[i][j][r]);
            }
        }
    }
}

// ===================== FALLBACK (round-2 kernels, fp32 weights) =============
__global__ __launch_bounds__(NTHREADS)
void dual_swiglu_fb(const unsigned short* __restrict__ Xb,
                    const float* __restrict__ WgAll,
                    const float* __restrict__ WuAll,
                    const float* __restrict__ Wsg,
                    const float* __restrict__ Wsu,
                    unsigned short* __restrict__ Ysparse,
                    unsigned short* __restrict__ Yshared,
                    const int* __restrict__ cnt,
                    const int* __restrict__ base,
                    const int* __restrict__ tok_list)
{
    const int z  = blockIdx.z;
    const bool shared_path = (z == 0);
    const int e  = z - 1;
    const int Icols = shared_path ? SIDIM : IDIM;
    const int m0 = blockIdx.y * 128;
    const int n0 = blockIdx.x * 64;
    if (n0 >= Icols) return;
    const int M = shared_path ? N_TOK : cnt[e];
    if (m0 >= M) return;
    const float* Wg = shared_path ? Wsg : WgAll + (size_t)e * HDIM * IDIM;
    const float* Wu = shared_path ? Wsu : WuAll + (size_t)e * HDIM * IDIM;
    unsigned short* Y = shared_path ? Yshared : Ysparse;
    const int yb = shared_path ? 0 : base[e];

    __shared__ short As[128 * 32];
    __shared__ short Gs[64 * 32];
    __shared__ short Us[64 * 32];

    const int tid  = threadIdx.x;
    const int lane = tid & 63;
    const int wave = tid >> 6;
    const int wm   = wave >> 1;
    const int wn   = wave & 1;
    const int l15  = lane & 15;
    const int q    = lane >> 4;

    const int ar = tid >> 1;
    const int at = tid & 1;
    const int slotA = m0 + ar;
    int xrow;
    if (!shared_path) xrow = tok_list[e * N_TOK + ((slotA < M) ? slotA : (M - 1))];
    else              xrow = slotA;
    const unsigned short* xp = Xb + (size_t)xrow * HDIM + at * 16;

    const int wcn = tid & 63;
    const int wcc = tid >> 6;
    const float* gp = Wg + n0 + wcn;
    const float* up = Wu + n0 + wcn;

    f32x4 accg[4][2], accu[4][2];
#pragma unroll
    for (int i = 0; i < 4; ++i)
#pragma unroll
        for (int j = 0; j < 2; ++j) {
            accg[i][j] = (f32x4){0.f, 0.f, 0.f, 0.f};
            accu[i][j] = (f32x4){0.f, 0.f, 0.f, 0.f};
        }

    uint4 a0, a1;
    float g8[8], u8[8];
    auto ldtile = [&](int kk) {
        a0 = *(const uint4*)(xp + kk);
        a1 = *(const uint4*)(xp + kk + 8);
#pragma unroll
        for (int j = 0; j < 8; ++j) {
            g8[j] = gp[(size_t)(kk + wcc * 8 + j) * Icols];
            u8[j] = up[(size_t)(kk + wcc * 8 + j) * Icols];
        }
    };

    ldtile(0);
    for (int k0 = 0; k0 < HDIM; k0 += 32) {
        __syncthreads();
        *(uint4*)(As + swz(ar, at * 2 + 0) * 8) = a0;
        *(uint4*)(As + swz(ar, at * 2 + 1) * 8) = a1;
        uint4 gw = make_uint4(cvtpk(g8[0], g8[1]), cvtpk(g8[2], g8[3]),
                              cvtpk(g8[4], g8[5]), cvtpk(g8[6], g8[7]));
        uint4 uw = make_uint4(cvtpk(u8[0], u8[1]), cvtpk(u8[2], u8[3]),
                              cvtpk(u8[4], u8[5]), cvtpk(u8[6], u8[7]));
        *(uint4*)(Gs + swz(wcn, wcc) * 8) = gw;
        *(uint4*)(Us + swz(wcn, wcc) * 8) = uw;
        __syncthreads();

        int kn = k0 + 32;
        if (kn >= HDIM) kn = k0;
        ldtile(kn);

        bf16x8 af[4], bg[2], bu[2];
#pragma unroll
        for (int i = 0; i < 4; ++i)
            af[i] = *(const bf16x8*)(As + swz(wm * 64 + i * 16 + l15, q) * 8);
#pragma unroll
        for (int j = 0; j < 2; ++j) {
            bg[j] = *(const bf16x8*)(Gs + swz(wn * 32 + j * 16 + l15, q) * 8);
            bu[j] = *(const bf16x8*)(Us + swz(wn * 32 + j * 16 + l15, q) * 8);
        }
#pragma unroll
        for (int i = 0; i < 4; ++i)
#pragma unroll
            for (int j = 0; j < 2; ++j) {
                accg[i][j] = __builtin_amdgcn_mfma_f32_16x16x32_bf16(af[i], bg[j], accg[i][j], 0, 0, 0);
                accu[i][j] = __builtin_amdgcn_mfma_f32_16x16x32_bf16(af[i], bu[j], accu[i][j], 0, 0, 0);
            }
    }

#pragma unroll
    for (int i = 0; i < 4; ++i) {
#pragma unroll
        for (int r = 0; r < 4; ++r) {
            const int slot = m0 + wm * 64 + i * 16 + q * 4 + r;
            if (slot < M) {
                unsigned short* yrow = Y + (size_t)(yb + slot) * Icols;
#pragma unroll
                for (int j = 0; j < 2; ++j) {
                    const int col = n0 + wn * 32 + j * 16 + l15;
                    float g = accg[i][j][r];
                    float u = accu[i][j][r];
                    float y = (g / (1.f + expf(-g))) * u;
                    yrow[col] = (unsigned short)f2bf_u(y);
                }
            }
        }
    }
}

__global__ __launch_bounds__(NTHREADS)
void down_fb(const unsigned short* __restrict__ Ash,
             const unsigned short* __restrict__ Asp,
             const float* __restrict__ Wsd,
             const float* __restrict__ WdAll,
             float* __restrict__ out,
             const int* __restrict__ cnt,
             const int* __restrict__ base,
             const int* __restrict__ tok_list,
             const float* __restrict__ wt_list)
{
    const int z  = blockIdx.z;
    const bool shared_path = (z == 0);
    const int e  = z - 1;
    const int K  = shared_path ? SIDIM : IDIM;
    const int m0 = blockIdx.y * 64;
    const int n0 = blockIdx.x * 128;
    const int M = shared_path ? N_TOK : cnt[e];
    if (m0 >= M) return;
    const unsigned short* A = shared_path ? Ash : Asp;
    const float* Wd = shared_path ? Wsd : WdAll + (size_t)e * IDIM * HDIM;
    const int yb = shared_path ? 0 : base[e];

    __shared__ short As[64 * 32];
    __shared__ short Bs[128 * 32];

    const int tid  = threadIdx.x;
    const int lane = tid & 63;
    const int wave = tid >> 6;
    const int wm   = wave >> 1;
    const int wn   = wave & 1;
    const int l15  = lane & 15;
    const int q    = lane >> 4;

    const int ar = tid >> 2;
    const int ac = tid & 3;
    const int slotA = m0 + ar;
    const int arow = yb + ((slotA < M) ? slotA : (M - 1));
    const unsigned short* ap = A + (size_t)arow * K + ac * 8;

    const int bn = tid & 127;
    const int bh = tid >> 7;
    const float* bp = Wd + n0 + bn;

    f32x4 acc[2][4];
#pragma unroll
    for (int i = 0; i < 2; ++i)
#pragma unroll
        for (int j = 0; j < 4; ++j) acc[i][j] = (f32x4){0.f, 0.f, 0.f, 0.f};

    uint4 a0;
    float b16[16];
    auto ldtile = [&](int kk) {
        a0 = *(const uint4*)(ap + kk);
#pragma unroll
        for (int c = 0; c < 2; ++c)
#pragma unroll
            for (int j = 0; j < 8; ++j)
                b16[c * 8 + j] = bp[(size_t)(kk + (bh * 2 + c) * 8 + j) * HDIM];
    };

    ldtile(0);
    for (int k0 = 0; k0 < K; k0 += 32) {
        __syncthreads();
        *(uint4*)(As + swz(ar, ac) * 8) = a0;
        uint4 w0 = make_uint4(cvtpk(b16[0], b16[1]),  cvtpk(b16[2], b16[3]),
                              cvtpk(b16[4], b16[5]),  cvtpk(b16[6], b16[7]));
        uint4 w1 = make_uint4(cvtpk(b16[8], b16[9]),  cvtpk(b16[10], b16[11]),
                              cvtpk(b16[12], b16[13]), cvtpk(b16[14], b16[15]));
        *(uint4*)(Bs + swz(bn, bh * 2 + 0) * 8) = w0;
        *(uint4*)(Bs + swz(bn, bh * 2 + 1) * 8) = w1;
        __syncthreads();

        int kn = k0 + 32;
        if (kn >= K) kn = k0;
        ldtile(kn);

        bf16x8 af[2], bfr[4];
#pragma unroll
        for (int i = 0; i < 2; ++i)
            af[i] = *(const bf16x8*)(As + swz(wm * 32 + i * 16 + l15, q) * 8);
#pragma unroll
        for (int j = 0; j < 4; ++j)
            bfr[j] = *(const bf16x8*)(Bs + swz(wn * 64 + j * 16 + l15, q) * 8);
#pragma unroll
        for (int i = 0; i < 2; ++i)
#pragma unroll
            for (int j = 0; j < 4; ++j)
                acc[i][j] = __builtin_amdgcn_mfma_f32_16x16x32_bf16(af[i], bfr[j], acc[i][j], 0, 0, 0);
    }

#pragma unroll
    for (int i = 0; i < 2; ++i) {
#pragma unroll
        for (int r = 0; r < 4; ++r) {
            const int slot = m0 + wm * 32 + i * 16 + q * 4 + r;
            if (slot >= M) continue;
            const int tok  = shared_path ? slot : tok_list[e * N_TOK + slot];
            const float wt = shared_path ? 1.f  : wt_list[e * N_TOK + slot];
            float* orow = out + (size_t)tok * HDIM;
#pragma unroll
            for (int j = 0; j < 4; ++j) {
                const int col = n0 + wn * 64 + j * 16 + l15;
                atomicAdd(&orow[col], wt * acc[i][j][r]);
            }
        }
    }
}

// ------------------------------------------------------------------ launch --
extern "C" void kernel_launch(void* const* d_in, const int* in_sizes, int n_in,
                              void* d_out, int out_size, void* d_ws, size_t ws_size,
                              hipStream_t stream)
{
    const float* x       = (const float*)d_in[0];
    const float* rw      = (const float*)d_in[1];
    const float* w_gate  = (const float*)d_in[2];
    const float* w_up    = (const float*)d_in[3];
    const float* w_down  = (const float*)d_in[4];
    const float* ws_gate = (const float*)d_in[5];
    const float* ws_up   = (const float*)d_in[6];
    const float* ws_down = (const float*)d_in[7];

    float* out    = (float*)d_out;                       // [N_TOK, HDIM]
    float* logits = out + (size_t)N_TOK * HDIM;          // [N_TOK, NEXP]

    char* w = (char*)d_ws;
    int* cnt      = (int*)w;                             // 16
    int* base     = cnt + 16;                            // 16
    int* tok_list = base + 16;                           // E*N
    float* wt_list = (float*)(tok_list + NEXP * N_TOK);  // E*N
    uintptr_t p = (uintptr_t)(wt_list + NEXP * N_TOK);
    p = (p + 255) & ~(uintptr_t)255;
    unsigned short* Xb       = (unsigned short*)p;                 // 8 MB
    unsigned short* A_shared = Xb + (size_t)N_TOK * HDIM;          // 8 MB
    unsigned short* Ybuf     = A_shared + (size_t)N_TOK * SIDIM;   // 8 MB
    unsigned short* WgT      = Ybuf + (size_t)2 * N_TOK * IDIM;    // 67 MB
    unsigned short* WuT      = WgT + (size_t)NEXP * IDIM * HDIM;   // 67 MB
    unsigned short* WdT      = WuT + (size_t)NEXP * IDIM * HDIM;   // 67 MB
    unsigned short* WsgT     = WdT + (size_t)NEXP * HDIM * IDIM;   // 8.4 MB
    unsigned short* WsuT     = WsgT + (size_t)SIDIM * HDIM;        // 8.4 MB
    unsigned short* WsdT     = WsuT + (size_t)SIDIM * HDIM;        // 8.4 MB
    const size_t need = (size_t)((char*)(WsdT + (size_t)HDIM * SIDIM) - (char*)d_ws);

    hipMemsetAsync(cnt, 0, 16 * sizeof(int), stream);
    hipMemsetAsync(out, 0, (size_t)N_TOK * HDIM * sizeof(float), stream);

    convert_x_kernel<<<dim3((N_TOK * HDIM) / (NTHREADS * 8)), dim3(NTHREADS), 0, stream>>>(x, Xb);
    router_kernel<<<dim3(N_TOK), dim3(NTHREADS), 0, stream>>>(
        x, rw, logits, cnt, tok_list, wt_list);
    prefix_kernel<<<dim3(1), dim3(64), 0, stream>>>(cnt, base);

    if (ws_size >= need) {
        // ---- fast path: bf16-transposed weights + global_load_lds GEMMs ----
        transpose_w<<<dim3(IDIM / 64, HDIM / 64, NEXP), dim3(NTHREADS), 0, stream>>>(
            w_gate, WgT, HDIM, IDIM);
        transpose_w<<<dim3(IDIM / 64, HDIM / 64, NEXP), dim3(NTHREADS), 0, stream>>>(
            w_up, WuT, HDIM, IDIM);
        transpose_w<<<dim3(HDIM / 64, IDIM / 64, NEXP), dim3(NTHREADS), 0, stream>>>(
            w_down, WdT, IDIM, HDIM);
        transpose_w<<<dim3(SIDIM / 64, HDIM / 64, 1), dim3(NTHREADS), 0, stream>>>(
            ws_gate, WsgT, HDIM, SIDIM);
        transpose_w<<<dim3(SIDIM / 64, HDIM / 64, 1), dim3(NTHREADS), 0, stream>>>(
            ws_up, WsuT, HDIM, SIDIM);
        transpose_w<<<dim3(HDIM / 64, SIDIM / 64, 1), dim3(NTHREADS), 0, stream>>>(
            ws_down, WsdT, SIDIM, HDIM);

        dual_swiglu_gl<<<dim3(SIDIM / 64, N_TOK / 128, NEXP + 1), dim3(NTHREADS), 0, stream>>>(
            Xb, WgT, WuT, WsgT, WsuT, Ybuf, A_shared, cnt, base, tok_list);
        down_gl<<<dim3(HDIM / 128, N_TOK / 64, NEXP + 1), dim3(NTHREADS), 0, stream>>>(
            A_shared, Ybuf, WsdT, WdT, out, cnt, base, tok_list, wt_list);
    } else {
        // ---- fallback: round-2 fp32-weight kernels ----
        dual_swiglu_fb<<<dim3(SIDIM / 64, N_TOK / 128, NEXP + 1), dim3(NTHREADS), 0, stream>>>(
            Xb, w_gate, w_up, ws_gate, ws_up, Ybuf, A_shared, cnt, base, tok_list);
        down_fb<<<dim3(HDIM / 128, N_TOK / 64, NEXP + 1), dim3(NTHREADS), 0, stream>>>(
            A_shared, Ybuf, ws_down, w_down, out, cnt, base, tok_list, wt_list);
    }
}